// Round 1
// 96.998 us; speedup vs baseline: 1.1431x; 1.1431x over previous
//
#include <hip/hip_runtime.h>
#include <hip/hip_cooperative_groups.h>

// S=32 systems, N=512 atoms/system, F=256 features
#define SY 32
#define NA 512
#define FD 256

typedef __attribute__((ext_vector_type(8))) short bf16x8;   // 8 bf16 = 4 VGPRs
typedef __attribute__((ext_vector_type(4))) short bf16x4;   // 4 bf16 = 8 B
typedef __attribute__((ext_vector_type(4))) float f32x4;    // MFMA C/D frag

static __device__ __forceinline__ short f2bf(float x) {
    union { float f; unsigned u; } v; v.f = x;
    unsigned r = v.u + 0x7fffu + ((v.u >> 16) & 1u);   // RNE
    return (short)(r >> 16);
}
static __device__ __forceinline__ float bf2f(short x) {
    union { float f; unsigned u; } v;
    v.u = ((unsigned)(unsigned short)x) << 16;
    return v.f;
}

// async 16B global->LDS (linear dest = wave-uniform base + lane*16)
static __device__ __forceinline__ void gld16(const void* g, void* l) {
    __builtin_amdgcn_global_load_lds(
        (const __attribute__((address_space(1))) void*)g,
        (__attribute__((address_space(3))) void*)l,
        16, 0, 0);
}

// ---------------------------------------------------------------------------
// Kernel 1 v2: charges = features @ W^T + b via bf16 MFMA (fp32 accum).
// 256 blocks x 512 threads (8 waves/CU): wave w owns f in [32w,32w+32).
// Fast path: writes ONLY qT bf16 [s][f][j] (coalesced via LDS transpose).
// Fallback path (qfp != nullptr): also writes fp32 q for lr_coop.
// ---------------------------------------------------------------------------
__global__ __launch_bounds__(512) void charges_mfma(
    const float* __restrict__ feat, const float* __restrict__ W,
    const float* __restrict__ b, float* __restrict__ qfp,
    short* __restrict__ qT)
{
    __shared__ __attribute__((aligned(16))) short sA[64 * 72];   //  9.2 KB
    __shared__ __attribute__((aligned(16))) short sB[256 * 72];  // 36.9 KB
    __shared__ __attribute__((aligned(16))) short tr[256 * 72];  // 36.9 KB
    const int t    = threadIdx.x;
    const int i0   = blockIdx.x * 64;
    const int w    = t >> 6;            // wave 0..7
    const int lane = t & 63;
    const int n16  = lane & 15;
    const int quad = lane >> 4;

    f32x4 acc[4][2];
    #pragma unroll
    for (int a = 0; a < 4; ++a)
        #pragma unroll
        for (int c = 0; c < 2; ++c) acc[a][c] = (f32x4)0.0f;

    for (int k0 = 0; k0 < FD; k0 += 64) {
        // stage feat tile 64i x 64k (2 float4/thread)
        #pragma unroll
        for (int m = 0; m < 2; ++m) {
            int lin = t + 512 * m;
            int i = lin >> 4, kq = lin & 15;
            float4 v = *(const float4*)&feat[(size_t)(i0 + i) * FD + k0 + 4 * kq];
            bf16x4 p; p[0] = f2bf(v.x); p[1] = f2bf(v.y);
                      p[2] = f2bf(v.z); p[3] = f2bf(v.w);
            *(bf16x4*)&sA[i * 72 + 4 * kq] = p;
        }
        // stage W tile 256f x 64k (8 float4/thread)
        #pragma unroll
        for (int m = 0; m < 8; ++m) {
            int lin = t + 512 * m;
            int f = lin >> 4, kq = lin & 15;
            float4 v = *(const float4*)&W[(size_t)f * FD + k0 + 4 * kq];
            bf16x4 p; p[0] = f2bf(v.x); p[1] = f2bf(v.y);
                      p[2] = f2bf(v.z); p[3] = f2bf(v.w);
            *(bf16x4*)&sB[f * 72 + 4 * kq] = p;
        }
        __syncthreads();

        #pragma unroll
        for (int ks = 0; ks < 64; ks += 32) {
            bf16x8 af[4], bfr[2];
            #pragma unroll
            for (int it = 0; it < 4; ++it)
                af[it] = *(const bf16x8*)&sA[(16 * it + n16) * 72 + ks + quad * 8];
            #pragma unroll
            for (int fb = 0; fb < 2; ++fb)
                bfr[fb] = *(const bf16x8*)&sB[(32 * w + 16 * fb + n16) * 72 + ks + quad * 8];
            #pragma unroll
            for (int it = 0; it < 4; ++it)
                #pragma unroll
                for (int fb = 0; fb < 2; ++fb)
                    acc[it][fb] = __builtin_amdgcn_mfma_f32_16x16x32_bf16(
                        af[it], bfr[fb], acc[it][fb], 0, 0, 0);
        }
        __syncthreads();
    }

    float bias[2];
    #pragma unroll
    for (int fb = 0; fb < 2; ++fb) bias[fb] = b[32 * w + 16 * fb + n16];

    if (qfp) {   // fallback path needs fp32 q
        #pragma unroll
        for (int it = 0; it < 4; ++it)
            #pragma unroll
            for (int fb = 0; fb < 2; ++fb)
                #pragma unroll
                for (int r = 0; r < 4; ++r) {
                    int i = i0 + 16 * it + 4 * quad + r;
                    int f = 32 * w + 16 * fb + n16;
                    qfp[(size_t)i * FD + f] = acc[it][fb][r] + bias[fb];
                }
    }

    // transpose to [f][i] bf16 in LDS, then coalesced 16B stores to qT
    #pragma unroll
    for (int it = 0; it < 4; ++it)
        #pragma unroll
        for (int fb = 0; fb < 2; ++fb) {
            bf16x4 p;
            #pragma unroll
            for (int r = 0; r < 4; ++r) p[r] = f2bf(acc[it][fb][r] + bias[fb]);
            int f = 32 * w + 16 * fb + n16;
            *(bf16x4*)&tr[f * 72 + 16 * it + 4 * quad] = p;
        }
    __syncthreads();
    {
        short* qTs = qT + ((size_t)(i0 >> 9)) * FD * NA;
        const int ilb = i0 & 511;
        #pragma unroll
        for (int n = 0; n < 4; ++n) {
            int S = n * 512 + t;        // 0..2047
            int f = S >> 3;
            int c = S & 7;
            uint4 v = *(const uint4*)&tr[f * 72 + c * 8];
            *(uint4*)&qTs[(size_t)f * NA + ilb + c * 8] = v;
        }
    }
}

// ---------------------------------------------------------------------------
// Kernel 2 FAST (non-coop): V = 0.5 * v @ q (bf16 MFMA), out = V * q.
// Grid 512 = (s = b&31 [XCD-local], ichunk = b>>5 of 32 rows); 2 blocks/CU.
// v4: j-tile widened 64 -> 128 (8 barriers instead of 16 per block);
//     q staged via global_load_lds dwordx4 with pre-swizzled per-lane source
//     (linear LDS dest, logical chunk c of row f lives at slot (c+f)&15).
//     LDS: 64K sqb + 8K svb + 6K pos = 78 KB -> still 2 blocks/CU.
// ---------------------------------------------------------------------------
__global__ __launch_bounds__(256, 2) void lr_fast(
    const float* __restrict__ pos, float* __restrict__ gbuf,
    const short* __restrict__ qT)
{
    __shared__ float px[NA], py[NA], pz[NA];
    __shared__ __attribute__((aligned(16))) short sqb[FD * 128];  // 64 KB [f][128j swz]
    __shared__ __attribute__((aligned(16))) short svb[32 * 128];  //  8 KB [i][128j swz]

    const int blk = blockIdx.x;
    const int s   = blk & 31;
    const int i0  = (blk >> 5) * 32;
    const int t   = threadIdx.x;
    const int w    = t >> 6;
    const int lane = t & 63;
    const int n16  = lane & 15;
    const int quad = lane >> 4;

    for (int m = t; m < NA; m += 256) {
        const float* p = &pos[((size_t)s * NA + m) * 3];
        px[m] = p[0]; py[m] = p[1]; pz[m] = p[2];
    }

    f32x4 acc[2][4];
    #pragma unroll
    for (int a = 0; a < 2; ++a)
        #pragma unroll
        for (int c = 0; c < 4; ++c) acc[a][c] = (f32x4)0.0f;
    float qreg[2][4][4];

    const short* qTs = qT + (size_t)s * FD * NA;
    const int pi = t & 31;        // pair-tile i
    const int pc = t >> 5;        // pair-tile j-chunk 0..7 (16 j each)
    const int gi = i0 + pi;
    const int wbase = t & ~63;    // w*64, wave-uniform

    __syncthreads();
    const float xi = px[gi], yi = py[gi], zi = pz[gi];

    for (int j0 = 0; j0 < NA; j0 += 128) {
        // ---- stage q tile: 256f x 128j bf16 via global_load_lds -----------
        // linear LDS slot Sl = n*256 + t holds row f=Sl>>4, phys chunk cs=Sl&15,
        // sourced from logical chunk c=(cs-f)&15 -> read swizzle is (c+f)&15.
        #pragma unroll
        for (int n = 0; n < 16; ++n) {
            int Sl = n * 256 + t;
            int f  = Sl >> 4;
            int cs = Sl & 15;
            int c  = (cs - f) & 15;
            gld16(&qTs[(size_t)f * NA + j0 + c * 8],
                  &sqb[(n * 256 + wbase) * 8]);     // uniform base + lane*16
        }
        // ---- v tile: 32i x 128j (16 pair evals/thread, hides load lat) ----
        bf16x8 vA, vB;
        #pragma unroll
        for (int jj = 0; jj < 8; ++jj) {
            int gj = j0 + pc * 16 + jj;
            float dx = xi - px[gj];
            float dy = yi - py[gj];
            float dz = zi - pz[gj];
            float r2 = dx * dx + dy * dy + dz * dz;
            float inv = __builtin_amdgcn_rsqf(r2);
            float dd  = r2 * inv;
            float sn = __sinf(dd * 0.31415926535f);
            float om = (dd < 5.0f) ? sn * sn : 1.0f;
            float vv = (gi != gj) ? 0.5f * om * inv : 0.0f;
            vA[jj] = f2bf(vv);
        }
        #pragma unroll
        for (int jj = 0; jj < 8; ++jj) {
            int gj = j0 + pc * 16 + 8 + jj;
            float dx = xi - px[gj];
            float dy = yi - py[gj];
            float dz = zi - pz[gj];
            float r2 = dx * dx + dy * dy + dz * dz;
            float inv = __builtin_amdgcn_rsqf(r2);
            float dd  = r2 * inv;
            float sn = __sinf(dd * 0.31415926535f);
            float om = (dd < 5.0f) ? sn * sn : 1.0f;
            float vv = (gi != gj) ? 0.5f * om * inv : 0.0f;
            vB[jj] = f2bf(vv);
        }
        *(bf16x8*)&svb[pi * 128 + (((2 * pc + pi) & 15) * 8)]     = vA;
        *(bf16x8*)&svb[pi * 128 + (((2 * pc + 1 + pi) & 15) * 8)] = vB;
        __syncthreads();

        // ---- own-tile q snapshot (once; uniform branch) ----
        if (j0 == (i0 & ~127)) {
            const int jb0 = i0 & 127;     // 0,32,64,96
            #pragma unroll
            for (int it = 0; it < 2; ++it)
                #pragma unroll
                for (int fb = 0; fb < 4; ++fb) {
                    int f = 64 * w + 16 * fb + n16;
                    #pragma unroll
                    for (int r = 0; r < 4; ++r) {
                        int jl = jb0 + 16 * it + 4 * quad + r;
                        int c  = jl >> 3, o = jl & 7;
                        qreg[it][fb][r] =
                            bf2f(sqb[f * 128 + (((c + f) & 15) * 8) + o]);
                    }
                }
        }

        // ---- fragments + MFMA: 4 kh x (2 it x 4 fb) = 32 mfma / wave ----
        #pragma unroll
        for (int kh = 0; kh < 4; ++kh) {
            const int c = kh * 4 + quad;          // logical 8-j chunk 0..15
            bf16x8 a0 = *(const bf16x8*)&svb[n16 * 128 + (((c + n16) & 15) * 8)];
            bf16x8 a1 = *(const bf16x8*)&svb[(16 + n16) * 128 + (((c + 16 + n16) & 15) * 8)];
            bf16x8 bq[4];
            #pragma unroll
            for (int fb = 0; fb < 4; ++fb) {
                int f = 64 * w + 16 * fb + n16;
                bq[fb] = *(const bf16x8*)&sqb[f * 128 + (((c + f) & 15) * 8)];
            }
            #pragma unroll
            for (int fb = 0; fb < 4; ++fb) {
                acc[0][fb] = __builtin_amdgcn_mfma_f32_16x16x32_bf16(
                    a0, bq[fb], acc[0][fb], 0, 0, 0);
                acc[1][fb] = __builtin_amdgcn_mfma_f32_16x16x32_bf16(
                    a1, bq[fb], acc[1][fb], 0, 0, 0);
            }
        }
        __syncthreads();
    }

    // epilogue: out = V * q  (pure store, q from registers)
    #pragma unroll
    for (int it = 0; it < 2; ++it)
        #pragma unroll
        for (int fb = 0; fb < 4; ++fb)
            #pragma unroll
            for (int r = 0; r < 4; ++r) {
                int i = i0 + 16 * it + 4 * quad + r;
                int f = 64 * w + 16 * fb + n16;
                size_t a = ((size_t)s * NA + i) * FD + f;
                gbuf[a] = acc[it][fb][r] * qreg[it][fb][r];
            }
}

// ---------------------------------------------------------------------------
// Kernel 2 FALLBACK (cooperative, validated round 4) — used if ws < 8 MB.
// ---------------------------------------------------------------------------
__global__ __launch_bounds__(256) void lr_coop(
    const float* __restrict__ pos, float* __restrict__ gbuf)
{
    __shared__ float px[NA], py[NA], pz[NA];
    __shared__ __attribute__((aligned(16))) short svb[64 * 40];
    __shared__ __attribute__((aligned(16))) short sqb[FD * 40];

    const int blk = blockIdx.x;
    const int s   = blk & 31;
    const int i0  = (blk >> 5) * 64;
    const int t   = threadIdx.x;
    const int w    = t >> 6;
    const int lane = t & 63;
    const int n16  = lane & 15;
    const int quad = lane >> 4;

    for (int m = t; m < NA; m += 256) {
        const float* p = &pos[((size_t)s * NA + m) * 3];
        px[m] = p[0]; py[m] = p[1]; pz[m] = p[2];
    }

    f32x4 acc[4][4];
    #pragma unroll
    for (int a = 0; a < 4; ++a)
        #pragma unroll
        for (int c = 0; c < 4; ++c) acc[a][c] = (f32x4)0.0f;

    __syncthreads();

    const int fq  = t >> 2;
    const int jb  = t & 3;
    const int iv  = t & 63;
    const int jbv = t >> 6;
    const int gi  = i0 + iv;

    float4 rq[8];
    #pragma unroll
    for (int m = 0; m < 8; ++m)
        rq[m] = *(const float4*)&gbuf[((size_t)s * NA + 8 * jb + m) * FD + 4 * fq];

    for (int j0 = 0; j0 < NA; j0 += 32) {
        bf16x8 vrow;
        #pragma unroll
        for (int jj = 0; jj < 8; ++jj) {
            int gj = j0 + 8 * jbv + jj;
            float dx = px[gi] - px[gj];
            float dy = py[gi] - py[gj];
            float dz = pz[gi] - pz[gj];
            float dd = sqrtf(dx * dx + dy * dy + dz * dz);
            float om = (dd < 5.0f) ? 0.5f * (1.0f - __cosf(dd * 0.62831853071795f))
                                   : 1.0f;
            float vv = (gi != gj) ? (0.5f * om * __builtin_amdgcn_rcpf(dd)) : 0.0f;
            vrow[jj] = f2bf(vv);
        }
        bf16x8 rows[4];
        #pragma unroll
        for (int m = 0; m < 8; ++m) {
            rows[0][m] = f2bf(rq[m].x);
            rows[1][m] = f2bf(rq[m].y);
            rows[2][m] = f2bf(rq[m].z);
            rows[3][m] = f2bf(rq[m].w);
        }
        #pragma unroll
        for (int d = 0; d < 4; ++d) {
            int f = 4 * fq + d;
            int phys = (jb + (f >> 3)) & 3;
            *(bf16x8*)&sqb[f * 40 + phys * 8] = rows[d];
        }
        {
            int phys = (jbv + (iv >> 3)) & 3;
            *(bf16x8*)&svb[iv * 40 + phys * 8] = vrow;
        }
        {
            int jn = (j0 + 32) & (NA - 1);
            #pragma unroll
            for (int m = 0; m < 8; ++m)
                rq[m] = *(const float4*)&gbuf[((size_t)s * NA + jn + 8 * jb + m) * FD + 4 * fq];
        }
        __syncthreads();

        bf16x8 af[4], bfr[4];
        #pragma unroll
        for (int it = 0; it < 4; ++it) {
            int i = 16 * it + n16;
            int phys = (quad + (i >> 3)) & 3;
            af[it] = *(const bf16x8*)&svb[i * 40 + phys * 8];
        }
        #pragma unroll
        for (int fb = 0; fb < 4; ++fb) {
            int f = 16 * (4 * w + fb) + n16;
            int phys = (quad + (f >> 3)) & 3;
            bfr[fb] = *(const bf16x8*)&sqb[f * 40 + phys * 8];
        }
        #pragma unroll
        for (int it = 0; it < 4; ++it)
            #pragma unroll
            for (int fb = 0; fb < 4; ++fb)
                acc[it][fb] = __builtin_amdgcn_mfma_f32_16x16x32_bf16(
                    af[it], bfr[fb], acc[it][fb], 0, 0, 0);
        __syncthreads();
    }

    cooperative_groups::this_grid().sync();

    #pragma unroll
    for (int it = 0; it < 4; ++it)
        #pragma unroll
        for (int fb = 0; fb < 4; ++fb)
            #pragma unroll
            for (int r = 0; r < 4; ++r) {
                int i = i0 + 16 * it + 4 * quad + r;
                int f = 16 * (4 * w + fb) + n16;
                size_t a = ((size_t)s * NA + i) * FD + f;
                gbuf[a] = acc[it][fb][r] * gbuf[a];
            }
}

extern "C" void kernel_launch(void* const* d_in, const int* in_sizes, int n_in,
                              void* d_out, int out_size, void* d_ws, size_t ws_size,
                              hipStream_t stream) {
    const float* positions = (const float*)d_in[0];  // [32,512,3]
    const float* features  = (const float*)d_in[1];  // [16384,256]
    const float* W         = (const float*)d_in[2];  // [256,256]
    const float* b         = (const float*)d_in[3];  // [256]
    float* gbuf = (float*)d_out;

    const size_t qT_bytes = (size_t)SY * NA * FD * sizeof(short);  // 8 MB
    const bool fast = (ws_size >= qT_bytes);
    short* qT = fast ? (short*)d_ws : nullptr;

    if (fast) {
        charges_mfma<<<dim3(256), 512, 0, stream>>>(features, W, b, nullptr, qT);
        lr_fast<<<dim3(512), 256, 0, stream>>>(positions, gbuf, qT);
    } else {
        // fallback: q fp32 in d_out, cooperative in-place update
        charges_mfma<<<dim3(256), 512, 0, stream>>>(features, W, b, gbuf,
                                                    (short*)d_out /*unused-safe*/);
        void* args[] = {(void*)&positions, (void*)&gbuf};
        hipLaunchCooperativeKernel((void*)lr_coop, dim3(256), dim3(256),
                                   args, 0, stream);
    }
}

// Round 3
// 96.472 us; speedup vs baseline: 1.1493x; 1.0055x over previous
//
#include <hip/hip_runtime.h>
#include <hip/hip_cooperative_groups.h>

// S=32 systems, N=512 atoms/system, F=256 features
#define SY 32
#define NA 512
#define FD 256

typedef __attribute__((ext_vector_type(8))) short bf16x8;   // 8 bf16 = 4 VGPRs
typedef __attribute__((ext_vector_type(4))) short bf16x4;   // 4 bf16 = 8 B
typedef __attribute__((ext_vector_type(4))) float f32x4;    // MFMA C/D frag

static __device__ __forceinline__ short f2bf(float x) {
    union { float f; unsigned u; } v; v.f = x;
    unsigned r = v.u + 0x7fffu + ((v.u >> 16) & 1u);   // RNE
    return (short)(r >> 16);
}
static __device__ __forceinline__ float bf2f(short x) {
    union { float f; unsigned u; } v;
    v.u = ((unsigned)(unsigned short)x) << 16;
    return v.f;
}

// async 16B global->LDS (linear dest = wave-uniform base + lane*16)
static __device__ __forceinline__ void gld16(const void* g, void* l) {
    __builtin_amdgcn_global_load_lds(
        (const __attribute__((address_space(1))) void*)g,
        (__attribute__((address_space(3))) void*)l,
        16, 0, 0);
}

// ---------------------------------------------------------------------------
// Kernel 1 v3: charges = features @ W^T + b via bf16 MFMA (fp32 accum).
// 512 blocks x 256 threads, 32-row tiles. LDS 41.5 KB (tr reuses sB)
// -> 2 blocks/CU co-resident: one block's compute hides the other's
// barrier drains (round-1 version was 83 KB -> 1 block/CU, fully serial
// at every __syncthreads). Writes ONLY qT bf16 [s][f][j].
// ---------------------------------------------------------------------------
__global__ __launch_bounds__(256, 2) void charges_v2(
    const float* __restrict__ feat, const float* __restrict__ W,
    const float* __restrict__ b, short* __restrict__ qT)
{
    __shared__ __attribute__((aligned(16))) short sA[32 * 72];   //  4.6 KB
    __shared__ __attribute__((aligned(16))) short sB[256 * 72];  // 36.9 KB
    short* tr = sB;                          // epilogue reuse: 256*40 shorts
    const int t    = threadIdx.x;
    const int i0   = blockIdx.x * 32;        // 512 blocks x 32 rows
    const int w    = t >> 6;                 // wave 0..3
    const int lane = t & 63;
    const int n16  = lane & 15;
    const int quad = lane >> 4;

    f32x4 acc[2][4];
    #pragma unroll
    for (int a = 0; a < 2; ++a)
        #pragma unroll
        for (int c = 0; c < 4; ++c) acc[a][c] = (f32x4)0.0f;

    for (int k0 = 0; k0 < FD; k0 += 64) {
        // stage feat tile 32i x 64k (2 float4/thread)
        #pragma unroll
        for (int m = 0; m < 2; ++m) {
            int lin = t + 256 * m;
            int i = lin >> 4, kq = lin & 15;
            float4 v = *(const float4*)&feat[(size_t)(i0 + i) * FD + k0 + 4 * kq];
            bf16x4 p; p[0] = f2bf(v.x); p[1] = f2bf(v.y);
                      p[2] = f2bf(v.z); p[3] = f2bf(v.w);
            *(bf16x4*)&sA[i * 72 + 4 * kq] = p;
        }
        // stage W tile 256f x 64k (16 float4/thread)
        #pragma unroll
        for (int m = 0; m < 16; ++m) {
            int lin = t + 256 * m;
            int f = lin >> 4, kq = lin & 15;
            float4 v = *(const float4*)&W[(size_t)f * FD + k0 + 4 * kq];
            bf16x4 p; p[0] = f2bf(v.x); p[1] = f2bf(v.y);
                      p[2] = f2bf(v.z); p[3] = f2bf(v.w);
            *(bf16x4*)&sB[f * 72 + 4 * kq] = p;
        }
        __syncthreads();

        #pragma unroll
        for (int ks = 0; ks < 64; ks += 32) {
            bf16x8 af[2], bfr[4];
            #pragma unroll
            for (int it = 0; it < 2; ++it)
                af[it] = *(const bf16x8*)&sA[(16 * it + n16) * 72 + ks + quad * 8];
            #pragma unroll
            for (int fb = 0; fb < 4; ++fb)
                bfr[fb] = *(const bf16x8*)&sB[(64 * w + 16 * fb + n16) * 72 + ks + quad * 8];
            __builtin_amdgcn_s_setprio(1);
            #pragma unroll
            for (int it = 0; it < 2; ++it)
                #pragma unroll
                for (int fb = 0; fb < 4; ++fb)
                    acc[it][fb] = __builtin_amdgcn_mfma_f32_16x16x32_bf16(
                        af[it], bfr[fb], acc[it][fb], 0, 0, 0);
            __builtin_amdgcn_s_setprio(0);
        }
        __syncthreads();
    }

    float bias[4];
    #pragma unroll
    for (int fb = 0; fb < 4; ++fb) bias[fb] = b[64 * w + 16 * fb + n16];

    // transpose to [f][i] bf16 (pitch 40) in reused sB, then 16B stores
    #pragma unroll
    for (int it = 0; it < 2; ++it)
        #pragma unroll
        for (int fb = 0; fb < 4; ++fb) {
            bf16x4 p;
            #pragma unroll
            for (int r = 0; r < 4; ++r) p[r] = f2bf(acc[it][fb][r] + bias[fb]);
            int f = 64 * w + 16 * fb + n16;
            *(bf16x4*)&tr[f * 40 + 16 * it + 4 * quad] = p;
        }
    __syncthreads();
    {
        short* qTs = qT + ((size_t)(i0 >> 9)) * FD * NA;
        const int ilb = i0 & 511;
        #pragma unroll
        for (int n = 0; n < 4; ++n) {
            int S = n * 256 + t;        // 0..1023
            int f = S >> 2;             // 0..255
            int c = S & 3;              // chunk of 8 atoms
            uint4 v = *(const uint4*)&tr[f * 40 + c * 8];
            *(uint4*)&qTs[(size_t)f * NA + ilb + c * 8] = v;
        }
    }
}

// ---------------------------------------------------------------------------
// Kernel 2 FAST (non-coop): V = 0.5 * v @ q (bf16 MFMA), out = V * q.
// Grid 512 = (s = b&31 [XCD-local], ichunk = b>>5 of 32 rows); 2 blocks/CU.
// 128-j tile, q staged via global_load_lds dwordx4 with pre-swizzled
// per-lane source (linear LDS dest). Identical to the round-1 PASSING
// version + s_setprio around the MFMA cluster (independent blocks/CU).
// ---------------------------------------------------------------------------
__global__ __launch_bounds__(256, 2) void lr_fast(
    const float* __restrict__ pos, float* __restrict__ gbuf,
    const short* __restrict__ qT)
{
    __shared__ float px[NA], py[NA], pz[NA];
    __shared__ __attribute__((aligned(16))) short sqb[FD * 128];  // 64 KB [f][128j swz]
    __shared__ __attribute__((aligned(16))) short svb[32 * 128];  //  8 KB [i][128j swz]

    const int blk = blockIdx.x;
    const int s   = blk & 31;
    const int i0  = (blk >> 5) * 32;
    const int t   = threadIdx.x;
    const int w    = t >> 6;
    const int lane = t & 63;
    const int n16  = lane & 15;
    const int quad = lane >> 4;

    for (int m = t; m < NA; m += 256) {
        const float* p = &pos[((size_t)s * NA + m) * 3];
        px[m] = p[0]; py[m] = p[1]; pz[m] = p[2];
    }

    f32x4 acc[2][4];
    #pragma unroll
    for (int a = 0; a < 2; ++a)
        #pragma unroll
        for (int c = 0; c < 4; ++c) acc[a][c] = (f32x4)0.0f;
    float qreg[2][4][4];

    const short* qTs = qT + (size_t)s * FD * NA;
    const int pi = t & 31;        // pair-tile i
    const int pc = t >> 5;        // pair-tile j-chunk 0..7 (16 j each)
    const int gi = i0 + pi;
    const int wbase = t & ~63;    // w*64, wave-uniform

    __syncthreads();
    const float xi = px[gi], yi = py[gi], zi = pz[gi];

    for (int j0 = 0; j0 < NA; j0 += 128) {
        // ---- stage q tile: 256f x 128j bf16 via global_load_lds -----------
        // linear LDS slot Sl = n*256 + t holds row f=Sl>>4, phys chunk cs=Sl&15,
        // sourced from logical chunk c=(cs-f)&15 -> read swizzle is (c+f)&15.
        #pragma unroll
        for (int n = 0; n < 16; ++n) {
            int Sl = n * 256 + t;
            int f  = Sl >> 4;
            int cs = Sl & 15;
            int c  = (cs - f) & 15;
            gld16(&qTs[(size_t)f * NA + j0 + c * 8],
                  &sqb[(n * 256 + wbase) * 8]);     // uniform base + lane*16
        }
        // ---- v tile: 32i x 128j (16 pair evals/thread, hides load lat) ----
        bf16x8 vA, vB;
        #pragma unroll
        for (int jj = 0; jj < 8; ++jj) {
            int gj = j0 + pc * 16 + jj;
            float dx = xi - px[gj];
            float dy = yi - py[gj];
            float dz = zi - pz[gj];
            float r2 = dx * dx + dy * dy + dz * dz;
            float inv = __builtin_amdgcn_rsqf(r2);
            float dd  = r2 * inv;
            float sn = __sinf(dd * 0.31415926535f);
            float om = (dd < 5.0f) ? sn * sn : 1.0f;
            float vv = (gi != gj) ? 0.5f * om * inv : 0.0f;
            vA[jj] = f2bf(vv);
        }
        #pragma unroll
        for (int jj = 0; jj < 8; ++jj) {
            int gj = j0 + pc * 16 + 8 + jj;
            float dx = xi - px[gj];
            float dy = yi - py[gj];
            float dz = zi - pz[gj];
            float r2 = dx * dx + dy * dy + dz * dz;
            float inv = __builtin_amdgcn_rsqf(r2);
            float dd  = r2 * inv;
            float sn = __sinf(dd * 0.31415926535f);
            float om = (dd < 5.0f) ? sn * sn : 1.0f;
            float vv = (gi != gj) ? 0.5f * om * inv : 0.0f;
            vB[jj] = f2bf(vv);
        }
        *(bf16x8*)&svb[pi * 128 + (((2 * pc + pi) & 15) * 8)]     = vA;
        *(bf16x8*)&svb[pi * 128 + (((2 * pc + 1 + pi) & 15) * 8)] = vB;
        __syncthreads();

        // ---- own-tile q snapshot (once; uniform branch) ----
        if (j0 == (i0 & ~127)) {
            const int jb0 = i0 & 127;     // 0,32,64,96
            #pragma unroll
            for (int it = 0; it < 2; ++it)
                #pragma unroll
                for (int fb = 0; fb < 4; ++fb) {
                    int f = 64 * w + 16 * fb + n16;
                    #pragma unroll
                    for (int r = 0; r < 4; ++r) {
                        int jl = jb0 + 16 * it + 4 * quad + r;
                        int c  = jl >> 3, o = jl & 7;
                        qreg[it][fb][r] =
                            bf2f(sqb[f * 128 + (((c + f) & 15) * 8) + o]);
                    }
                }
        }

        // ---- fragments + MFMA: 4 kh x (2 it x 4 fb) = 32 mfma / wave ----
        #pragma unroll
        for (int kh = 0; kh < 4; ++kh) {
            const int c = kh * 4 + quad;          // logical 8-j chunk 0..15
            bf16x8 a0 = *(const bf16x8*)&svb[n16 * 128 + (((c + n16) & 15) * 8)];
            bf16x8 a1 = *(const bf16x8*)&svb[(16 + n16) * 128 + (((c + 16 + n16) & 15) * 8)];
            bf16x8 bq[4];
            #pragma unroll
            for (int fb = 0; fb < 4; ++fb) {
                int f = 64 * w + 16 * fb + n16;
                bq[fb] = *(const bf16x8*)&sqb[f * 128 + (((c + f) & 15) * 8)];
            }
            __builtin_amdgcn_s_setprio(1);
            #pragma unroll
            for (int fb = 0; fb < 4; ++fb) {
                acc[0][fb] = __builtin_amdgcn_mfma_f32_16x16x32_bf16(
                    a0, bq[fb], acc[0][fb], 0, 0, 0);
                acc[1][fb] = __builtin_amdgcn_mfma_f32_16x16x32_bf16(
                    a1, bq[fb], acc[1][fb], 0, 0, 0);
            }
            __builtin_amdgcn_s_setprio(0);
        }
        __syncthreads();
    }

    // epilogue: out = V * q  (pure store, q from registers)
    #pragma unroll
    for (int it = 0; it < 2; ++it)
        #pragma unroll
        for (int fb = 0; fb < 4; ++fb)
            #pragma unroll
            for (int r = 0; r < 4; ++r) {
                int i = i0 + 16 * it + 4 * quad + r;
                int f = 64 * w + 16 * fb + n16;
                size_t a = ((size_t)s * NA + i) * FD + f;
                gbuf[a] = acc[it][fb][r] * qreg[it][fb][r];
            }
}

// ---------------------------------------------------------------------------
// FALLBACK kernels (used if ws < 8 MB) — unchanged, validated earlier.
// ---------------------------------------------------------------------------
__global__ __launch_bounds__(512) void charges_mfma(
    const float* __restrict__ feat, const float* __restrict__ W,
    const float* __restrict__ b, float* __restrict__ qfp,
    short* __restrict__ qT)
{
    __shared__ __attribute__((aligned(16))) short sA[64 * 72];
    __shared__ __attribute__((aligned(16))) short sB[256 * 72];
    __shared__ __attribute__((aligned(16))) short tr[256 * 72];
    const int t    = threadIdx.x;
    const int i0   = blockIdx.x * 64;
    const int w    = t >> 6;
    const int lane = t & 63;
    const int n16  = lane & 15;
    const int quad = lane >> 4;

    f32x4 acc[4][2];
    #pragma unroll
    for (int a = 0; a < 4; ++a)
        #pragma unroll
        for (int c = 0; c < 2; ++c) acc[a][c] = (f32x4)0.0f;

    for (int k0 = 0; k0 < FD; k0 += 64) {
        #pragma unroll
        for (int m = 0; m < 2; ++m) {
            int lin = t + 512 * m;
            int i = lin >> 4, kq = lin & 15;
            float4 v = *(const float4*)&feat[(size_t)(i0 + i) * FD + k0 + 4 * kq];
            bf16x4 p; p[0] = f2bf(v.x); p[1] = f2bf(v.y);
                      p[2] = f2bf(v.z); p[3] = f2bf(v.w);
            *(bf16x4*)&sA[i * 72 + 4 * kq] = p;
        }
        #pragma unroll
        for (int m = 0; m < 8; ++m) {
            int lin = t + 512 * m;
            int f = lin >> 4, kq = lin & 15;
            float4 v = *(const float4*)&W[(size_t)f * FD + k0 + 4 * kq];
            bf16x4 p; p[0] = f2bf(v.x); p[1] = f2bf(v.y);
                      p[2] = f2bf(v.z); p[3] = f2bf(v.w);
            *(bf16x4*)&sB[f * 72 + 4 * kq] = p;
        }
        __syncthreads();

        #pragma unroll
        for (int ks = 0; ks < 64; ks += 32) {
            bf16x8 af[4], bfr[2];
            #pragma unroll
            for (int it = 0; it < 4; ++it)
                af[it] = *(const bf16x8*)&sA[(16 * it + n16) * 72 + ks + quad * 8];
            #pragma unroll
            for (int fb = 0; fb < 2; ++fb)
                bfr[fb] = *(const bf16x8*)&sB[(32 * w + 16 * fb + n16) * 72 + ks + quad * 8];
            #pragma unroll
            for (int it = 0; it < 4; ++it)
                #pragma unroll
                for (int fb = 0; fb < 2; ++fb)
                    acc[it][fb] = __builtin_amdgcn_mfma_f32_16x16x32_bf16(
                        af[it], bfr[fb], acc[it][fb], 0, 0, 0);
        }
        __syncthreads();
    }

    float bias[2];
    #pragma unroll
    for (int fb = 0; fb < 2; ++fb) bias[fb] = b[32 * w + 16 * fb + n16];

    if (qfp) {
        #pragma unroll
        for (int it = 0; it < 4; ++it)
            #pragma unroll
            for (int fb = 0; fb < 2; ++fb)
                #pragma unroll
                for (int r = 0; r < 4; ++r) {
                    int i = i0 + 16 * it + 4 * quad + r;
                    int f = 32 * w + 16 * fb + n16;
                    qfp[(size_t)i * FD + f] = acc[it][fb][r] + bias[fb];
                }
    }

    #pragma unroll
    for (int it = 0; it < 4; ++it)
        #pragma unroll
        for (int fb = 0; fb < 2; ++fb) {
            bf16x4 p;
            #pragma unroll
            for (int r = 0; r < 4; ++r) p[r] = f2bf(acc[it][fb][r] + bias[fb]);
            int f = 32 * w + 16 * fb + n16;
            *(bf16x4*)&tr[f * 72 + 16 * it + 4 * quad] = p;
        }
    __syncthreads();
    {
        short* qTs = qT + ((size_t)(i0 >> 9)) * FD * NA;
        const int ilb = i0 & 511;
        #pragma unroll
        for (int n = 0; n < 4; ++n) {
            int S = n * 512 + t;
            int f = S >> 3;
            int c = S & 7;
            uint4 v = *(const uint4*)&tr[f * 72 + c * 8];
            *(uint4*)&qTs[(size_t)f * NA + ilb + c * 8] = v;
        }
    }
}

__global__ __launch_bounds__(256) void lr_coop(
    const float* __restrict__ pos, float* __restrict__ gbuf)
{
    __shared__ float px[NA], py[NA], pz[NA];
    __shared__ __attribute__((aligned(16))) short svb[64 * 40];
    __shared__ __attribute__((aligned(16))) short sqb[FD * 40];

    const int blk = blockIdx.x;
    const int s   = blk & 31;
    const int i0  = (blk >> 5) * 64;
    const int t   = threadIdx.x;
    const int w    = t >> 6;
    const int lane = t & 63;
    const int n16  = lane & 15;
    const int quad = lane >> 4;

    for (int m = t; m < NA; m += 256) {
        const float* p = &pos[((size_t)s * NA + m) * 3];
        px[m] = p[0]; py[m] = p[1]; pz[m] = p[2];
    }

    f32x4 acc[4][4];
    #pragma unroll
    for (int a = 0; a < 4; ++a)
        #pragma unroll
        for (int c = 0; c < 4; ++c) acc[a][c] = (f32x4)0.0f;

    __syncthreads();

    const int fq  = t >> 2;
    const int jb  = t & 3;
    const int iv  = t & 63;
    const int jbv = t >> 6;
    const int gi  = i0 + iv;

    float4 rq[8];
    #pragma unroll
    for (int m = 0; m < 8; ++m)
        rq[m] = *(const float4*)&gbuf[((size_t)s * NA + 8 * jb + m) * FD + 4 * fq];

    for (int j0 = 0; j0 < NA; j0 += 32) {
        bf16x8 vrow;
        #pragma unroll
        for (int jj = 0; jj < 8; ++jj) {
            int gj = j0 + 8 * jbv + jj;
            float dx = px[gi] - px[gj];
            float dy = py[gi] - py[gj];
            float dz = pz[gi] - pz[gj];
            float dd = sqrtf(dx * dx + dy * dy + dz * dz);
            float om = (dd < 5.0f) ? 0.5f * (1.0f - __cosf(dd * 0.62831853071795f))
                                   : 1.0f;
            float vv = (gi != gj) ? (0.5f * om * __builtin_amdgcn_rcpf(dd)) : 0.0f;
            vrow[jj] = f2bf(vv);
        }
        bf16x8 rows[4];
        #pragma unroll
        for (int m = 0; m < 8; ++m) {
            rows[0][m] = f2bf(rq[m].x);
            rows[1][m] = f2bf(rq[m].y);
            rows[2][m] = f2bf(rq[m].z);
            rows[3][m] = f2bf(rq[m].w);
        }
        #pragma unroll
        for (int d = 0; d < 4; ++d) {
            int f = 4 * fq + d;
            int phys = (jb + (f >> 3)) & 3;
            *(bf16x8*)&sqb[f * 40 + phys * 8] = rows[d];
        }
        {
            int phys = (jbv + (iv >> 3)) & 3;
            *(bf16x8*)&svb[iv * 40 + phys * 8] = vrow;
        }
        {
            int jn = (j0 + 32) & (NA - 1);
            #pragma unroll
            for (int m = 0; m < 8; ++m)
                rq[m] = *(const float4*)&gbuf[((size_t)s * NA + jn + 8 * jb + m) * FD + 4 * fq];
        }
        __syncthreads();

        bf16x8 af[4], bfr[4];
        #pragma unroll
        for (int it = 0; it < 4; ++it) {
            int i = 16 * it + n16;
            int phys = (quad + (i >> 3)) & 3;
            af[it] = *(const bf16x8*)&svb[i * 40 + phys * 8];
        }
        #pragma unroll
        for (int fb = 0; fb < 4; ++fb) {
            int f = 16 * (4 * w + fb) + n16;
            int phys = (quad + (f >> 3)) & 3;
            bfr[fb] = *(const bf16x8*)&sqb[f * 40 + phys * 8];
        }
        #pragma unroll
        for (int it = 0; it < 4; ++it)
            #pragma unroll
            for (int fb = 0; fb < 4; ++fb)
                acc[it][fb] = __builtin_amdgcn_mfma_f32_16x16x32_bf16(
                    af[it], bfr[fb], acc[it][fb], 0, 0, 0);
        __syncthreads();
    }

    cooperative_groups::this_grid().sync();

    #pragma unroll
    for (int it = 0; it < 4; ++it)
        #pragma unroll
        for (int fb = 0; fb < 4; ++fb)
            #pragma unroll
            for (int r = 0; r < 4; ++r) {
                int i = i0 + 16 * it + 4 * quad + r;
                int f = 16 * (4 * w + fb) + n16;
                size_t a = ((size_t)s * NA + i) * FD + f;
                gbuf[a] = acc[it][fb][r] * gbuf[a];
            }
}

extern "C" void kernel_launch(void* const* d_in, const int* in_sizes, int n_in,
                              void* d_out, int out_size, void* d_ws, size_t ws_size,
                              hipStream_t stream) {
    const float* positions = (const float*)d_in[0];  // [32,512,3]
    const float* features  = (const float*)d_in[1];  // [16384,256]
    const float* W         = (const float*)d_in[2];  // [256,256]
    const float* b         = (const float*)d_in[3];  // [256]
    float* gbuf = (float*)d_out;

    const size_t qT_bytes = (size_t)SY * NA * FD * sizeof(short);  // 8 MB
    const bool fast = (ws_size >= qT_bytes);
    short* qT = fast ? (short*)d_ws : nullptr;

    if (fast) {
        charges_v2<<<dim3(512), 256, 0, stream>>>(features, W, b, qT);
        lr_fast<<<dim3(512), 256, 0, stream>>>(positions, gbuf, qT);
    } else {
        // fallback: q fp32 in d_out, cooperative in-place update
        charges_mfma<<<dim3(256), 512, 0, stream>>>(features, W, b, gbuf,
                                                    (short*)d_out /*unused-safe*/);
        void* args[] = {(void*)&positions, (void*)&gbuf};
        hipLaunchCooperativeKernel((void*)lr_coop, dim3(256), dim3(256),
                                   args, 0, stream);
    }
}